// Round 3
// baseline (2752.411 us; speedup 1.0000x reference)
//
#include <hip/hip_runtime.h>

#define N_USERS 100000
#define N_ITEMS 200000
#define N_NODES 300000
#define EMB 64
#define NNZ_C 9600000
#define SCAN_BLK 1024
#define N_SCAN_BLOCKS ((N_NODES + SCAN_BLK - 1) / SCAN_BLK)   // 293

#define RPB 128                       // rows per bucket
#define RPB_SHIFT 7
#define NBUCKETS ((N_NODES + RPB - 1) / RPB)                  // 2344
#define CAP 5120                      // LDS staging capacity (mean 4096, max ~4350)
#define COL_BITS 19
#define COL_MASK 0x7FFFFu

// ==================== small utility kernels ====================

__global__ void zero_int_kernel(int* __restrict__ p, int n) {
    int stride = gridDim.x * blockDim.x;
    for (int i = blockIdx.x * blockDim.x + threadIdx.x; i < n; i += stride) p[i] = 0;
}

__global__ void hist_kernel(const int* __restrict__ rows, int* __restrict__ counts) {
    int stride = gridDim.x * blockDim.x;
    for (int e = blockIdx.x * blockDim.x + threadIdx.x; e < NNZ_C; e += stride)
        atomicAdd(&counts[rows[e]], 1);
}

// per-block exclusive scan of counts chunk -> row_ptr (partial), block total -> blockSums
__global__ void scan_a_kernel(const int* __restrict__ counts, int* __restrict__ row_ptr,
                              int* __restrict__ blockSums) {
    __shared__ int s[SCAN_BLK];
    int tid = threadIdx.x;
    int idx = blockIdx.x * SCAN_BLK + tid;
    int x = (idx < N_NODES) ? counts[idx] : 0;
    s[tid] = x;
    __syncthreads();
    for (int off = 1; off < SCAN_BLK; off <<= 1) {
        int t = (tid >= off) ? s[tid - off] : 0;
        __syncthreads();
        s[tid] += t;
        __syncthreads();
    }
    if (idx < N_NODES) row_ptr[idx] = s[tid] - x;
    if (tid == SCAN_BLK - 1) blockSums[blockIdx.x] = s[tid];
}

__global__ void scan_b_kernel(int* __restrict__ blockSums) {
    __shared__ int s[512];
    int tid = threadIdx.x;
    int x = (tid < N_SCAN_BLOCKS) ? blockSums[tid] : 0;
    s[tid] = x;
    __syncthreads();
    for (int off = 1; off < 512; off <<= 1) {
        int t = (tid >= off) ? s[tid - off] : 0;
        __syncthreads();
        s[tid] += t;
        __syncthreads();
    }
    if (tid < N_SCAN_BLOCKS) blockSums[tid] = s[tid] - x;
}

__global__ void scan_c_kernel(int* __restrict__ row_ptr, const int* __restrict__ blockSums,
                              int* __restrict__ offsets) {
    int tid = threadIdx.x;
    int idx = blockIdx.x * SCAN_BLK + tid;
    if (idx < N_NODES) {
        int v = row_ptr[idx] + blockSums[blockIdx.x];
        row_ptr[idx] = v;
        offsets[idx] = v;
    }
    if (blockIdx.x == 0 && tid == 0) row_ptr[N_NODES] = NNZ_C;
}

__global__ void cursor_init_kernel(const int* __restrict__ row_ptr, int* __restrict__ cursor) {
    int b = blockIdx.x * blockDim.x + threadIdx.x;
    if (b < NBUCKETS) cursor[b] = row_ptr[b * RPB];
}

// ==================== pass A: bin edges by 128-row bucket ====================
// binbuf[pos] = { (rloc<<19)|col , bits(val) } ; appends per bucket -> ~2344 hot lines
__global__ void binA_kernel(const int* __restrict__ rows, const int* __restrict__ cols,
                            const float* __restrict__ vals, int* __restrict__ cursor,
                            uint2* __restrict__ binbuf) {
    int stride = gridDim.x * blockDim.x;
    for (int e = blockIdx.x * blockDim.x + threadIdx.x; e < NNZ_C; e += stride) {
        int r = rows[e];
        int b = r >> RPB_SHIFT;
        int pos = atomicAdd(&cursor[b], 1);
        unsigned packed = ((unsigned)(r & (RPB - 1)) << COL_BITS) | (unsigned)cols[e];
        binbuf[pos] = make_uint2(packed, __float_as_uint(vals[e]));
    }
}

// ==================== pass B: per-bucket LDS counting sort -> cv ====================
// one block per bucket; cv writes land in a 32KB window owned by this block's XCD L2
__global__ void binB_kernel(const uint2* __restrict__ binbuf, const int* __restrict__ row_ptr,
                            int* __restrict__ offsets, uint2* __restrict__ cv) {
    __shared__ uint2 stage[CAP];
    __shared__ int cnt[RPB];
    __shared__ int cur[RPB];
    int b = blockIdx.x;
    int tid = threadIdx.x;
    int rbeg = b * RPB;
    int rend = min(rbeg + RPB, N_NODES);
    int ebeg = row_ptr[rbeg];
    int eend = row_ptr[rend];
    int E = eend - ebeg;

    if (E <= CAP) {
        for (int i = tid; i < E; i += blockDim.x) stage[i] = binbuf[ebeg + i];
        if (tid < RPB) cnt[tid] = 0;
        __syncthreads();
        for (int i = tid; i < E; i += blockDim.x)
            atomicAdd(&cnt[stage[i].x >> COL_BITS], 1);
        __syncthreads();
        // Hillis-Steele inclusive scan over 128 -> exclusive bases in cur
        if (tid < RPB) cur[tid] = cnt[tid];
        __syncthreads();
        for (int off = 1; off < RPB; off <<= 1) {
            int t = (tid < RPB && tid >= off) ? cur[tid - off] : 0;
            __syncthreads();
            if (tid < RPB) cur[tid] += t;
            __syncthreads();
        }
        if (tid < RPB) cur[tid] -= cnt[tid];   // exclusive base, used as cursor
        __syncthreads();
        for (int i = tid; i < E; i += blockDim.x) {
            uint2 p = stage[i];
            int rl = p.x >> COL_BITS;
            int pos = atomicAdd(&cur[rl], 1);
            cv[ebeg + pos] = make_uint2(p.x & COL_MASK, p.y);
        }
    } else {
        // statistically-unreachable overflow fallback: global atomic scatter
        for (int i = tid; i < E; i += blockDim.x) {
            uint2 p = binbuf[ebeg + i];
            int r = rbeg + (int)(p.x >> COL_BITS);
            int pos = atomicAdd(&offsets[r], 1);
            cv[pos] = make_uint2(p.x & COL_MASK, p.y);
        }
    }
}

// ==================== segmented SpMM, no atomics ====================
// one 16-lane sub-wave (x float4 = 64 floats) per row; fused acc update.
// gathers from gu/gi with split (layer 1: user/item inputs; later: ego, split=N_NODES)
__device__ __forceinline__ float4 gat(const float4* __restrict__ gu, const float4* __restrict__ gi,
                                      int split, int c, int lane) {
    return (c < split) ? gu[c * 16 + lane] : gi[(c - split) * 16 + lane];
}

__global__ void spmm_seg_kernel(const int* __restrict__ row_ptr, const uint2* __restrict__ cv,
                                const float4* __restrict__ gu, const float4* __restrict__ gi,
                                int split,
                                float4* __restrict__ ego_out, float4* __restrict__ acc,
                                float scale, int write_ego, int init_acc) {
    int sub = (blockIdx.x * blockDim.x + threadIdx.x) >> 4;
    int lane = threadIdx.x & 15;
    int nsub = (gridDim.x * blockDim.x) >> 4;
    for (int r = sub; r < N_NODES; r += nsub) {
        int beg = row_ptr[r], end = row_ptr[r + 1];
        float4 s0 = make_float4(0.f, 0.f, 0.f, 0.f);
        float4 s1 = make_float4(0.f, 0.f, 0.f, 0.f);
        float4 s2 = make_float4(0.f, 0.f, 0.f, 0.f);
        float4 s3 = make_float4(0.f, 0.f, 0.f, 0.f);
        int e = beg;
        for (; e + 4 <= end; e += 4) {
            uint2 p0 = cv[e], p1 = cv[e + 1], p2 = cv[e + 2], p3 = cv[e + 3];
            float4 x0 = gat(gu, gi, split, (int)p0.x, lane);
            float4 x1 = gat(gu, gi, split, (int)p1.x, lane);
            float4 x2 = gat(gu, gi, split, (int)p2.x, lane);
            float4 x3 = gat(gu, gi, split, (int)p3.x, lane);
            float v0 = __uint_as_float(p0.y), v1 = __uint_as_float(p1.y);
            float v2 = __uint_as_float(p2.y), v3 = __uint_as_float(p3.y);
            s0.x += v0 * x0.x; s0.y += v0 * x0.y; s0.z += v0 * x0.z; s0.w += v0 * x0.w;
            s1.x += v1 * x1.x; s1.y += v1 * x1.y; s1.z += v1 * x1.z; s1.w += v1 * x1.w;
            s2.x += v2 * x2.x; s2.y += v2 * x2.y; s2.z += v2 * x2.z; s2.w += v2 * x2.w;
            s3.x += v3 * x3.x; s3.y += v3 * x3.y; s3.z += v3 * x3.z; s3.w += v3 * x3.w;
        }
        for (; e < end; ++e) {
            uint2 p0 = cv[e];
            float4 x0 = gat(gu, gi, split, (int)p0.x, lane);
            float v0 = __uint_as_float(p0.y);
            s0.x += v0 * x0.x; s0.y += v0 * x0.y; s0.z += v0 * x0.z; s0.w += v0 * x0.w;
        }
        float4 s = make_float4(s0.x + s1.x + s2.x + s3.x, s0.y + s1.y + s2.y + s3.y,
                               s0.z + s1.z + s2.z + s3.z, s0.w + s1.w + s2.w + s3.w);
        int o = r * 16 + lane;
        float4 a;
        if (init_acc) {
            // layer 1: acc starts at ego0 (own row from inputs), no acc read
            a = (r < N_USERS) ? gu[r * 16 + lane] : gi[(r - N_USERS) * 16 + lane];
        } else {
            a = acc[o];
        }
        a.x = (a.x + s.x) * scale;
        a.y = (a.y + s.y) * scale;
        a.z = (a.z + s.z) * scale;
        a.w = (a.w + s.w) * scale;
        acc[o] = a;
        if (write_ego) ego_out[o] = s;
    }
}

// ==================== fallback (round-1 atomic path) ====================

__global__ void init_kernel(const float4* __restrict__ ue, const float4* __restrict__ ie,
                            float4* __restrict__ ego, float4* __restrict__ acc) {
    const int user4 = N_USERS * EMB / 4;
    const int total4 = N_NODES * EMB / 4;
    int stride = gridDim.x * blockDim.x;
    for (int i = blockIdx.x * blockDim.x + threadIdx.x; i < total4; i += stride) {
        float4 v = (i < user4) ? ue[i] : ie[i - user4];
        ego[i] = v;
        acc[i] = v;
    }
}

__global__ void zero4_kernel(float4* __restrict__ p, int n4) {
    int stride = gridDim.x * blockDim.x;
    float4 z = make_float4(0.f, 0.f, 0.f, 0.f);
    for (int i = blockIdx.x * blockDim.x + threadIdx.x; i < n4; i += stride) p[i] = z;
}

__global__ void spmm_atomic_kernel(const int* __restrict__ rows, const int* __restrict__ cols,
                                   const float* __restrict__ vals,
                                   const float* __restrict__ ego_in, float* __restrict__ ego_out) {
    int wave = (blockIdx.x * blockDim.x + threadIdx.x) >> 6;
    int lane = threadIdx.x & 63;
    int nwaves = (gridDim.x * blockDim.x) >> 6;
    for (int e = wave; e < NNZ_C; e += nwaves) {
        int r = rows[e];
        int c = cols[e];
        float v = vals[e];
        float x = ego_in[c * EMB + lane];
        atomicAdd(&ego_out[r * EMB + lane], v * x);
    }
}

__global__ void add_kernel(float4* __restrict__ acc, const float4* __restrict__ ego,
                           float scale, int n4) {
    int stride = gridDim.x * blockDim.x;
    for (int i = blockIdx.x * blockDim.x + threadIdx.x; i < n4; i += stride) {
        float4 a = acc[i];
        float4 g = ego[i];
        a.x = (a.x + g.x) * scale;
        a.y = (a.y + g.y) * scale;
        a.z = (a.z + g.z) * scale;
        a.w = (a.w + g.w) * scale;
        acc[i] = a;
    }
}

// ==================== launch ====================

extern "C" void kernel_launch(void* const* d_in, const int* in_sizes, int n_in,
                              void* d_out, int out_size, void* d_ws, size_t ws_size,
                              hipStream_t stream) {
    const float* user_emb = (const float*)d_in[0];
    const float* item_emb = (const float*)d_in[1];
    const int*   adj_rows = (const int*)d_in[2];
    const int*   adj_cols = (const int*)d_in[3];
    const float* adj_vals = (const float*)d_in[4];
    float* acc = (float*)d_out;

    const size_t egoN = (size_t)N_NODES * EMB;               // 19.2M floats = 76.8MB
    float* ego_a = (float*)d_ws;
    float* ego_b = ego_a + egoN;
    uint2* cv        = (uint2*)(ego_b + egoN);               // 76.8 MB
    int*   row_ptr   = (int*)(cv + (size_t)NNZ_C);           // N+1
    int*   offsets   = row_ptr + (N_NODES + 1);
    int*   counts    = offsets + N_NODES;
    int*   blockSums = counts + N_NODES;                     // 512
    int*   cursor    = blockSums + 512;                      // NBUCKETS
    size_t needed = (size_t)((char*)(cursor + NBUCKETS) - (char*)d_ws);

    // binbuf aliases ego_a (dead before any ego use): NNZ*8B == egoN*4B exactly
    uint2* binbuf = (uint2*)ego_a;

    const int total4 = N_NODES * EMB / 4;
    const int EW_BLOCKS = 4096, EW_THREADS = 256;

    if (ws_size >= needed) {
        // ---- build CSR via bucketed two-pass counting sort ----
        zero_int_kernel<<<1024, 256, 0, stream>>>(counts, N_NODES);
        hist_kernel<<<4096, 256, 0, stream>>>(adj_rows, counts);
        scan_a_kernel<<<N_SCAN_BLOCKS, SCAN_BLK, 0, stream>>>(counts, row_ptr, blockSums);
        scan_b_kernel<<<1, 512, 0, stream>>>(blockSums);
        scan_c_kernel<<<N_SCAN_BLOCKS, SCAN_BLK, 0, stream>>>(row_ptr, blockSums, offsets);
        cursor_init_kernel<<<(NBUCKETS + 255) / 256, 256, 0, stream>>>(row_ptr, cursor);
        binA_kernel<<<4096, 256, 0, stream>>>(adj_rows, adj_cols, adj_vals, cursor, binbuf);
        binB_kernel<<<NBUCKETS, 256, 0, stream>>>(binbuf, row_ptr, offsets, cv);

        // ---- propagate (init fused into layer 1) ----
        // L1: inputs -> ego_b, acc = ego0 + s
        spmm_seg_kernel<<<2048, 256, 0, stream>>>(row_ptr, cv,
            (const float4*)user_emb, (const float4*)item_emb, N_USERS,
            (float4*)ego_b, (float4*)acc, 1.0f, 1, 1);
        // L2: ego_b -> ego_a, acc += s
        spmm_seg_kernel<<<2048, 256, 0, stream>>>(row_ptr, cv,
            (const float4*)ego_b, (const float4*)ego_b, N_NODES,
            (float4*)ego_a, (float4*)acc, 1.0f, 1, 0);
        // L3: ego_a -> (none), acc = (acc + s) * 0.25
        spmm_seg_kernel<<<2048, 256, 0, stream>>>(row_ptr, cv,
            (const float4*)ego_a, (const float4*)ego_a, N_NODES,
            (float4*)ego_b, (float4*)acc, 0.25f, 0, 0);
    } else {
        // ---- fallback: atomic COO path ----
        init_kernel<<<EW_BLOCKS, EW_THREADS, 0, stream>>>(
            (const float4*)user_emb, (const float4*)item_emb,
            (float4*)ego_a, (float4*)acc);
        float* ego_in = ego_a;
        float* ego_out = ego_b;
        for (int layer = 0; layer < 3; ++layer) {
            zero4_kernel<<<EW_BLOCKS, EW_THREADS, 0, stream>>>((float4*)ego_out, total4);
            spmm_atomic_kernel<<<4096, 256, 0, stream>>>(
                adj_rows, adj_cols, adj_vals, ego_in, ego_out);
            float scale = (layer == 2) ? 0.25f : 1.0f;
            add_kernel<<<EW_BLOCKS, EW_THREADS, 0, stream>>>(
                (float4*)acc, (const float4*)ego_out, scale, total4);
            float* t = ego_in; ego_in = ego_out; ego_out = t;
        }
    }
}